// Round 9
// baseline (208.484 us; speedup 1.0000x reference)
//
#include <hip/hip_runtime.h>
#include <hip/hip_bf16.h>

// MultiHeadAttention B=2,S=2048,D=1024,H=16,Dh=64. fp32 I/O, bf16 MFMA compute.
// R17: attn key-parity wave split (waves 0-3 even K/V tiles, 4-7 odd) on top
// of the R14/R16 machinery: 512 threads, 16 waves/CU (4/SIMD, was 2/SIMD),
// per-wave 16 single-tile rounds with DMA staging, counted vmcnt(4), zero-
// conflict XOR-swizzled [64][64] tiles, in-register P (swapped QK^T +
// c-ordered V). Partial O/l merged additively in LDS epilogue (static-max =>
// exact). launch_bounds (512,4) = 128-VGPR cap >= ~116 live (NOT R12's
// (512,6) spill trap). s_setprio(1) around MFMA clusters (m191: attn +).
// GEMMs keep R11 counted-vmcnt pipeline + R15 quad swizzle; XCD swizzle kept.

typedef short bf16x8 __attribute__((ext_vector_type(8)));
typedef short bf16x4 __attribute__((ext_vector_type(4)));
typedef float f32x4  __attribute__((ext_vector_type(4)));

constexpr size_t NE = (size_t)4096 * 1024;   // elems of [B*S, D]
constexpr size_t NW = (size_t)1024 * 1024;   // elems of [D, D]

#if __has_builtin(__builtin_amdgcn_exp2f)
#define EXP2(x) __builtin_amdgcn_exp2f(x)
#else
#define EXP2(x) exp2f(x)
#endif

__device__ __forceinline__ short f2bf(float f) {
  __hip_bfloat16 h = __float2bfloat16(f);
  return *reinterpret_cast<short*>(&h);
}

__device__ __forceinline__ void cp16(const short* g, short* l) {
  __builtin_amdgcn_global_load_lds(
      (const __attribute__((address_space(1))) void*)g,
      (__attribute__((address_space(3))) void*)l, 16, 0, 0);
}

// bijective XCD-chunked remap; requires nblk % 8 == 0.
__device__ __forceinline__ int xcd_swz(int x, int nblk) {
  return (x & 7) * (nblk >> 3) + (x >> 3);
}

// ---------------- fused fp32 -> bf16 conversion, 16 slices of 1M elems
__global__ __launch_bounds__(256) void cvt_kernel(
    const float* q, const float* k, const float* v,
    const float* Wq, const float* Wk, const float* Wv, const float* Wo,
    short* qb, short* kb, short* vb,
    short* Wqb, short* Wkb, short* Wvb, short* Wob) {
  const int y = blockIdx.y;
  const float* s; short* d;
  if (y < 12) {
    const int t = y >> 2;
    const size_t off = (size_t)(y & 3) << 20;
    s = (t == 0 ? q : (t == 1 ? k : v)) + off;
    d = (t == 0 ? qb : (t == 1 ? kb : vb)) + off;
  } else {
    s = (y == 12 ? Wq : (y == 13 ? Wk : (y == 14 ? Wv : Wo)));
    d = (y == 12 ? Wqb : (y == 13 ? Wkb : (y == 14 ? Wvb : Wob)));
  }
  size_t i = (size_t)blockIdx.x * 256 + threadIdx.x;
  float4 val = ((const float4*)s)[i];
  bf16x4 o;
  o[0] = f2bf(val.x); o[1] = f2bf(val.y); o[2] = f2bf(val.z); o[3] = f2bf(val.w);
  ((bf16x4*)d)[i] = o;
}

// ---------------- fused Q/K/V projection GEMM: C = (A @ W^T + b) * scale
// 128x128 tile, BK=32 x 32 rounds, triple-buffered counted-vmcnt pipeline.
// LDS panels quad-swizzled: physical quad = logical ^ ((row>>1)&3).
__global__ __launch_bounds__(256) void gemm_qkv(
    const short* __restrict__ A0, const short* __restrict__ A1, const short* __restrict__ A2,
    const short* __restrict__ W0, const short* __restrict__ W1, const short* __restrict__ W2,
    const float* __restrict__ b0, const float* __restrict__ b1, const float* __restrict__ b2,
    short* __restrict__ C0, short* __restrict__ C1, short* __restrict__ Cv) {
  __shared__ short As[3][128 * 32];
  __shared__ short Bs[3][128 * 32];
  const int which = blockIdx.y;
  const short* A    = which == 0 ? A0 : (which == 1 ? A1 : A2);
  const short* W    = which == 0 ? W0 : (which == 1 ? W1 : W2);
  const float* bias = which == 0 ? b0 : (which == 1 ? b1 : b2);
  const float scale = which == 0 ? 0.18033688011112042f : 1.0f;  // 0.125*log2e

  const int tid  = threadIdx.x;
  const int bx   = xcd_swz((int)blockIdx.x, 256);  // XCD owns 4 bm x 8 bn chunk
  const int bm   = bx >> 3;
  const int bn   = bx & 7;
  const int lane = tid & 63, wid = tid >> 6;
  const int g = lane >> 4, l15 = lane & 15;
  const int wm = (wid >> 1) * 64, wn = (wid & 1) * 64;
  const int sk = (l15 >> 1) & 3;                   // read-side swizzle key

  // staging source quad pre-swizzled so physical quad q holds logical
  // q ^ ((row>>1)&3): lane writes physical (tid&3), so source quad is
  // (tid&3) ^ ((tid>>3)&3)  [row = tid>>2].
  const int qsw = ((tid & 3) ^ ((tid >> 3) & 3)) * 8;
  const short* Ag = A + (size_t)(bm * 128 + (tid >> 2)) * 1024 + qsw;
  const short* Wg = W + (size_t)(bn * 128 + (tid >> 2)) * 1024 + qsw;
  const int wofs = wid * 512;

  // stage round t (cols t*32..t*32+31) into buffer b: 4 vmem instrs/wave
#define QKV_STAGE(t, b)                               \
  do {                                                \
    const int kk_ = (t) * 32;                         \
    cp16(Ag + kk_,             As[(b)] + wofs);       \
    cp16(Ag + 64 * 1024 + kk_, As[(b)] + wofs + 2048);\
    cp16(Wg + kk_,             Bs[(b)] + wofs);       \
    cp16(Wg + 64 * 1024 + kk_, Bs[(b)] + wofs + 2048);\
  } while (0)

  f32x4 acc[4][4];
#pragma unroll
  for (int i = 0; i < 4; ++i)
#pragma unroll
    for (int j = 0; j < 4; ++j) acc[i][j] = (f32x4){0.f, 0.f, 0.f, 0.f};

  QKV_STAGE(0, 0);
  QKV_STAGE(1, 1);

  for (int t = 0; t < 32; ++t) {
    const int cur = t % 3;
    if (t < 30) {
      QKV_STAGE(t + 2, (t + 2) % 3);
      asm volatile("s_waitcnt vmcnt(8)" ::: "memory");   // round-t loads done
    } else if (t == 30) {
      asm volatile("s_waitcnt vmcnt(4)" ::: "memory");
    } else {
      asm volatile("s_waitcnt vmcnt(0)" ::: "memory");
    }
    __builtin_amdgcn_s_barrier();

    bf16x8 af[4], bfr[4];
#pragma unroll
    for (int mt = 0; mt < 4; ++mt)
      af[mt] = *(const bf16x8*)&As[cur][(wm + mt * 16 + l15) * 32 + ((g ^ sk)) * 8];
#pragma unroll
    for (int nt = 0; nt < 4; ++nt)
      bfr[nt] = *(const bf16x8*)&Bs[cur][(wn + nt * 16 + l15) * 32 + ((g ^ sk)) * 8];
#pragma unroll
    for (int mt = 0; mt < 4; ++mt)
#pragma unroll
      for (int nt = 0; nt < 4; ++nt)
        acc[mt][nt] = __builtin_amdgcn_mfma_f32_16x16x32_bf16(
            af[mt], bfr[nt], acc[mt][nt], 0, 0, 0);

    asm volatile("s_waitcnt lgkmcnt(0)" ::: "memory");   // LDS reads retired
    __builtin_amdgcn_s_barrier();                        // vmcnt NOT drained
  }
#undef QKV_STAGE

  const int col0 = bn * 128 + wn;
  if (which < 2) {
    short* C = which == 0 ? C0 : C1;
#pragma unroll
    for (int nt = 0; nt < 4; ++nt) {
      const int col = col0 + nt * 16 + l15;
      const float bb = bias[col];
#pragma unroll
      for (int mt = 0; mt < 4; ++mt) {
        const int m0 = bm * 128 + wm + mt * 16 + g * 4;
#pragma unroll
        for (int r = 0; r < 4; ++r)
          C[(size_t)(m0 + r) * 1024 + col] = f2bf((acc[mt][nt][r] + bb) * scale);
      }
    }
  } else {
    // V: write transposed per head [b,h,dh,slot], key-dim c-permuted within
    // each 64-key tile: c(k6) = (nt6&2)*16 + g6*8 + (nt6&1)*4 + r6, matching
    // attn's in-register P fragment slot order.
#pragma unroll
    for (int nt = 0; nt < 4; ++nt) {
      const int col = col0 + nt * 16 + l15;
      const int h = col >> 6, dh = col & 63;
      const float bb = bias[col];
#pragma unroll
      for (int mt = 0; mt < 4; ++mt) {
        const int m0 = bm * 128 + wm + mt * 16 + g * 4;   // 4-aligned, same b
        const int bb_ = m0 >> 11, s0 = m0 & 2047;
        const int k6 = s0 & 63;                           // k6&3 == 0
        const int cpos = (s0 & ~63) | (((k6 >> 4) & 2) << 4)
                       | (((k6 >> 2) & 3) << 3) | (((k6 >> 4) & 1) << 2);
        bf16x4 o;
#pragma unroll
        for (int r = 0; r < 4; ++r) o[r] = f2bf(acc[mt][nt][r] + bb);
        *(bf16x4*)&Cv[(((size_t)bb_ * 16 + h) * 64 + dh) * 2048 + cpos] = o;
      }
    }
  }
}

// ---------------- output projection: fp32 out = A(bf16) @ W^T + b
// 64x128 tile, BK=32 x 32 rounds, triple-buffered counted-vmcnt pipeline.
// Same quad swizzle as gemm_qkv.
__global__ __launch_bounds__(256) void gemm_out(
    const short* __restrict__ A, const short* __restrict__ W,
    const float* __restrict__ bias, float* __restrict__ C) {
  __shared__ short As[3][64 * 32];
  __shared__ short Bs[3][128 * 32];
  const int tid  = threadIdx.x;
  const int bx   = xcd_swz((int)blockIdx.x, 512);  // XCD owns 8 bm x 8 bn chunk
  const int bm   = bx >> 3;    // 64 M-tiles
  const int bn   = bx & 7;     // 8 N-tiles
  const int lane = tid & 63, wid = tid >> 6;
  const int g = lane >> 4, l15 = lane & 15;
  const int wm = (wid >> 1) * 32, wn = (wid & 1) * 64;
  const int sk = (l15 >> 1) & 3;

  const int qsw = ((tid & 3) ^ ((tid >> 3) & 3)) * 8;
  const short* Ag = A + (size_t)(bm * 64 + (tid >> 2)) * 1024 + qsw;
  const short* Wg = W + (size_t)(bn * 128 + (tid >> 2)) * 1024 + qsw;
  const int wofs = wid * 512;

  // stage round t into buffer b: 3 vmem instrs/wave
#define OUT_STAGE(t, b)                               \
  do {                                                \
    const int kk_ = (t) * 32;                         \
    cp16(Ag + kk_,             As[(b)] + wofs);       \
    cp16(Wg + kk_,             Bs[(b)] + wofs);       \
    cp16(Wg + 64 * 1024 + kk_, Bs[(b)] + wofs + 2048);\
  } while (0)

  f32x4 acc[2][4];
#pragma unroll
  for (int i = 0; i < 2; ++i)
#pragma unroll
    for (int j = 0; j < 4; ++j) acc[i][j] = (f32x4){0.f, 0.f, 0.f, 0.f};

  OUT_STAGE(0, 0);
  OUT_STAGE(1, 1);

  for (int t = 0; t < 32; ++t) {
    const int cur = t % 3;
    if (t < 30) {
      OUT_STAGE(t + 2, (t + 2) % 3);
      asm volatile("s_waitcnt vmcnt(6)" ::: "memory");   // round-t loads done
    } else if (t == 30) {
      asm volatile("s_waitcnt vmcnt(3)" ::: "memory");
    } else {
      asm volatile("s_waitcnt vmcnt(0)" ::: "memory");
    }
    __builtin_amdgcn_s_barrier();

    bf16x8 af[2], bfr[4];
#pragma unroll
    for (int mt = 0; mt < 2; ++mt)
      af[mt] = *(const bf16x8*)&As[cur][(wm + mt * 16 + l15) * 32 + ((g ^ sk)) * 8];
#pragma unroll
    for (int nt = 0; nt < 4; ++nt)
      bfr[nt] = *(const bf16x8*)&Bs[cur][(wn + nt * 16 + l15) * 32 + ((g ^ sk)) * 8];
#pragma unroll
    for (int mt = 0; mt < 2; ++mt)
#pragma unroll
      for (int nt = 0; nt < 4; ++nt)
        acc[mt][nt] = __builtin_amdgcn_mfma_f32_16x16x32_bf16(
            af[mt], bfr[nt], acc[mt][nt], 0, 0, 0);

    asm volatile("s_waitcnt lgkmcnt(0)" ::: "memory");
    __builtin_amdgcn_s_barrier();                        // vmcnt NOT drained
  }
#undef OUT_STAGE

  const int col0 = bn * 128 + wn;
#pragma unroll
  for (int nt = 0; nt < 4; ++nt) {
    const int col = col0 + nt * 16 + l15;
    const float bb = bias[col];
#pragma unroll
    for (int mt = 0; mt < 2; ++mt) {
      const int m0 = bm * 64 + wm + mt * 16 + g * 4;
#pragma unroll
      for (int r = 0; r < 4; ++r)
        C[(size_t)(m0 + r) * 1024 + col] = acc[mt][nt][r] + bb;
    }
  }
}

// ---------------- flash attention, static-max exp2 softmax, full keys.
// 512 threads / 8 waves: waves 0-3 even K/V tiles, 4-7 odd (16 rounds each).
// Per wave: 32 q-rows, in-register P (swapped QK^T + c-ordered V), DMA
// staging with counted vmcnt(4), XOR quad-swizzled [64][64] tiles
// (conflicts=0). Partial O/l merged additively in LDS epilogue.
// 16 waves/CU (4/SIMD) vs R16's 8 -- the q-row/wave count caps 8/CU without
// a key split. launch_bounds (512,4): 128-VGPR cap >= ~116 live.
__global__ __launch_bounds__(512, 4) void attn_kernel(
    const short* __restrict__ Q, const short* __restrict__ K,
    const short* __restrict__ Vg, short* __restrict__ O) {
  __shared__ __align__(16) char smem[65536];
  short (*KT)[2][64 * 64] = (short(*)[2][64 * 64])smem;            // [par][buf]
  short (*VT)[2][64 * 64] = (short(*)[2][64 * 64])(smem + 32768);  // [par][buf]
  float* M = (float*)smem;                                         // epilogue

  const int tid  = threadIdx.x;
  const int bx   = xcd_swz((int)blockIdx.x, 512);  // XCD owns 4 (b,h) groups
  const int qt   = bx & 15;    // 16 q-tiles of 128 rows
  const int bh   = bx >> 4;    // 32 (b,h)
  const int b    = bh >> 4, h = bh & 15;
  const int lane = tid & 63, wid = tid >> 6;   // wid 0..7
  const int par  = wid >> 2;                   // key-tile parity group
  const int w4   = wid & 3;                    // q-subtile within group
  const int g = lane >> 4, l15 = lane & 15;
  const int sx = l15 & 7;                      // read-side swizzle key

  const int q0 = qt * 128 + w4 * 32;
  bf16x8 qf[2][2];
#pragma unroll
  for (int mt = 0; mt < 2; ++mt) {
    const size_t base = (size_t)(b * 2048 + q0 + mt * 16 + l15) * 1024 + h * 64;
    qf[mt][0] = *(const bf16x8*)(Q + base + g * 8);
    qf[mt][1] = *(const bf16x8*)(Q + base + 32 + g * 8);
  }

  // O^T accumulator: o_acc[mt][nt][r] = O[q = mt*16+l15][dh = nt*16+g*4+r]
  f32x4 o_acc[2][4];
#pragma unroll
  for (int i = 0; i < 2; ++i)
#pragma unroll
    for (int j = 0; j < 4; ++j) o_acc[i][j] = (f32x4){0.f, 0.f, 0.f, 0.f};
  float l_i[2] = {0.f, 0.f};

  // DMA staging: each parity's wave w4 owns rows w4*16..w4*16+15 of its tile.
  // Lane l writes physical quad (row = r0 + (l>>3), q = l&7); source chunk
  // qc = (l&7) ^ (l>>3) so logical chunk c sits at physical c ^ (row&7).
  const int lrow = lane >> 3;
  const int qc   = (lane & 7) ^ lrow;
  const int r0   = w4 * 16;
  const short* KgA = K + (size_t)(b * 2048 + r0 + lrow) * 1024 + h * 64 + qc * 8;
  const short* VgA = Vg + (size_t)((b * 16 + h) * 64 + r0 + lrow) * 2048 + qc * 8;

  // stage key-tile tk into this parity's buffer bf: 4 vmem instrs/thread
#define ATTN_STAGE(tk_, bf_)                                                  \
  do {                                                                        \
    cp16(KgA + (size_t)(tk_) * 64 * 1024,       &KT[par][bf_][r0 * 64]);      \
    cp16(KgA + (size_t)((tk_) * 64 + 8) * 1024, &KT[par][bf_][(r0 + 8) * 64]);\
    cp16(VgA + (tk_) * 64,                      &VT[par][bf_][r0 * 64]);      \
    cp16(VgA + (tk_) * 64 + 8 * 2048,           &VT[par][bf_][(r0 + 8) * 64]);\
  } while (0)

  ATTN_STAGE(par, 0);

  for (int ktp = 0; ktp < 16; ++ktp) {
    const int cur = ktp & 1;
    if (ktp < 15) {
      ATTN_STAGE(2 * (ktp + 1) + par, cur ^ 1);
      asm volatile("s_waitcnt vmcnt(4)" ::: "memory");   // this round's loads
    } else {
      asm volatile("s_waitcnt vmcnt(0)" ::: "memory");
    }
    __builtin_amdgcn_s_barrier();

    // S^T = K Q^T (exp2 domain): lane holds S[key=nt*16+g*4+r][q=mt*16+l15]
    f32x4 sv[2][4];
    __builtin_amdgcn_s_setprio(1);
#pragma unroll
    for (int nt = 0; nt < 4; ++nt) {
      const int krow = (nt * 16 + l15) * 64;
      bf16x8 kf0 = *(const bf16x8*)&KT[par][cur][krow + ((g ^ sx) << 3)];
      bf16x8 kf1 = *(const bf16x8*)&KT[par][cur][krow + (((g + 4) ^ sx) << 3)];
#pragma unroll
      for (int mt = 0; mt < 2; ++mt) {
        f32x4 z = (f32x4){0.f, 0.f, 0.f, 0.f};
        z = __builtin_amdgcn_mfma_f32_16x16x32_bf16(kf0, qf[mt][0], z, 0, 0, 0);
        z = __builtin_amdgcn_mfma_f32_16x16x32_bf16(kf1, qf[mt][1], z, 0, 0, 0);
        sv[mt][nt] = z;
      }
    }
    __builtin_amdgcn_s_setprio(0);

    // static-max softmax in-register: p = exp2(s); lane's 16 values pack
    // into its PV B-frag (slot c = (nt&2)*16 + g*8 + (nt&1)*4 + r)
    bf16x8 pf[2][2];
#pragma unroll
    for (int mt = 0; mt < 2; ++mt) {
      float s = 0.f;
#pragma unroll
      for (int nt = 0; nt < 4; ++nt)
#pragma unroll
        for (int r = 0; r < 4; ++r) {
          float p = EXP2(sv[mt][nt][r]);
          s += p;
          pf[mt][nt >> 1][(nt & 1) * 4 + r] = f2bf(p);
        }
      l_i[mt] += s;
    }

    // O^T += V^T P^T : A = vf (dh rows, c slots), B = pf (q cols, c slots)
    __builtin_amdgcn_s_setprio(1);
#pragma unroll
    for (int nt = 0; nt < 4; ++nt) {
      const int vrow = (nt * 16 + l15) * 64;
      bf16x8 vf0 = *(const bf16x8*)&VT[par][cur][vrow + ((g ^ sx) << 3)];
      bf16x8 vf1 = *(const bf16x8*)&VT[par][cur][vrow + (((g + 4) ^ sx) << 3)];
#pragma unroll
      for (int mt = 0; mt < 2; ++mt) {
        o_acc[mt][nt] = __builtin_amdgcn_mfma_f32_16x16x32_bf16(
            vf0, pf[mt][0], o_acc[mt][nt], 0, 0, 0);
        o_acc[mt][nt] = __builtin_amdgcn_mfma_f32_16x16x32_bf16(
            vf1, pf[mt][1], o_acc[mt][nt], 0, 0, 0);
      }
    }
    __builtin_amdgcn_s_setprio(0);

    asm volatile("s_waitcnt lgkmcnt(0)" ::: "memory");   // LDS reads retired
    __builtin_amdgcn_s_barrier();                        // vmcnt NOT drained
  }
#undef ATTN_STAGE

  // merge parity-1 partials into parity-0 via LDS (34 floats, stride 36)
  if (par == 1) {
    float* dst = M + (size_t)(w4 * 64 + lane) * 36;
#pragma unroll
    for (int mt = 0; mt < 2; ++mt)
#pragma unroll
      for (int nt = 0; nt < 4; ++nt)
        *(f32x4*)(dst + (mt * 4 + nt) * 4) = o_acc[mt][nt];
    dst[32] = l_i[0];
    dst[33] = l_i[1];
  }
  __syncthreads();
  if (par == 0) {
    const float* src = M + (size_t)(w4 * 64 + lane) * 36;
#pragma unroll
    for (int mt = 0; mt < 2; ++mt)
#pragma unroll
      for (int nt = 0; nt < 4; ++nt)
        o_acc[mt][nt] += *(const f32x4*)(src + (mt * 4 + nt) * 4);
    l_i[0] += src[32];
    l_i[1] += src[33];

    // epilogue: reduce l across the 4 g-groups, normalize, store bf16x4
#pragma unroll
    for (int mt = 0; mt < 2; ++mt) {
      float l = l_i[mt];
      l += __shfl_xor(l, 16, 64);
      l += __shfl_xor(l, 32, 64);
      const float inv = 1.0f / l;
      const int row = q0 + mt * 16 + l15;
      const size_t base = (size_t)(b * 2048 + row) * 1024 + h * 64;
#pragma unroll
      for (int nt = 0; nt < 4; ++nt) {
        bf16x4 o;
#pragma unroll
        for (int r = 0; r < 4; ++r) o[r] = f2bf(o_acc[mt][nt][r] * inv);
        *(bf16x4*)&O[base + nt * 16 + g * 4] = o;
      }
    }
  }
}

extern "C" void kernel_launch(void* const* d_in, const int* in_sizes, int n_in,
                              void* d_out, int out_size, void* d_ws, size_t ws_size,
                              hipStream_t stream) {
  (void)in_sizes; (void)n_in; (void)out_size; (void)ws_size;
  const float* q  = (const float*)d_in[0];
  const float* k  = (const float*)d_in[1];
  const float* v  = (const float*)d_in[2];
  const float* Wq = (const float*)d_in[3];
  const float* bq = (const float*)d_in[4];
  const float* Wk = (const float*)d_in[5];
  const float* bk = (const float*)d_in[6];
  const float* Wv = (const float*)d_in[7];
  const float* bv = (const float*)d_in[8];
  const float* Wo = (const float*)d_in[9];
  const float* bo = (const float*)d_in[10];
  float* out = (float*)d_out;

  short* qb  = (short*)d_ws;       // bf16 inputs
  short* kb  = qb + NE;
  short* vb  = kb + NE;
  short* Wqb = vb + NE;            // bf16 weights
  short* Wkb = Wqb + NW;
  short* Wvb = Wkb + NW;
  short* Wob = Wvb + NW;
  short* Qw  = Wob + NW;           // projected Q (pre-scaled)
  short* Kw  = Qw + NE;
  short* Vtg = Kw + NE;            // projected V [b,h,dh,slot] (c-ordered)
  short* Ob  = qb;                 // attention out (qb dead after gemm_qkv)

  cvt_kernel<<<dim3(1024, 16), 256, 0, stream>>>(q, k, v, Wq, Wk, Wv, Wo,
                                                 qb, kb, vb, Wqb, Wkb, Wvb, Wob);
  gemm_qkv<<<dim3(256, 3), 256, 0, stream>>>(qb, kb, vb, Wqb, Wkb, Wvb,
                                             bq, bk, bv, Qw, Kw, Vtg);
  attn_kernel<<<512, 512, 0, stream>>>(Qw, Kw, Vtg, Ob);
  gemm_out<<<512, 256, 0, stream>>>(Ob, Wob, bo, out);
}

// Round 10
// 201.892 us; speedup vs baseline: 1.0327x; 1.0327x over previous
//
#include <hip/hip_runtime.h>
#include <hip/hip_bf16.h>

// MultiHeadAttention B=2,S=2048,D=1024,H=16,Dh=64. fp32 I/O, bf16 MFMA compute.
// R18: gemm_out BK 32->64: 16 barrier rounds (was 32), [*][64] panels with
// 8-chunk XOR swizzle (phys = chunk ^ (row&7), source pre-swizzled
// (l&7)^(l>>3); consecutive-8-lane groups cover all 8 bank-quads ->
// conflict-free), double-buffered, 6 loads/round, steady vmcnt(6), 48KB LDS.
// cvt_kernel: 32B load + 16B store per lane (2x float4 -> bf16x8).
// attn (R17 parity-split) and gemm_qkv (R15 swizzle + R11 pipeline) unchanged.

typedef short bf16x8 __attribute__((ext_vector_type(8)));
typedef short bf16x4 __attribute__((ext_vector_type(4)));
typedef float f32x4  __attribute__((ext_vector_type(4)));

constexpr size_t NE = (size_t)4096 * 1024;   // elems of [B*S, D]
constexpr size_t NW = (size_t)1024 * 1024;   // elems of [D, D]

#if __has_builtin(__builtin_amdgcn_exp2f)
#define EXP2(x) __builtin_amdgcn_exp2f(x)
#else
#define EXP2(x) exp2f(x)
#endif

__device__ __forceinline__ short f2bf(float f) {
  __hip_bfloat16 h = __float2bfloat16(f);
  return *reinterpret_cast<short*>(&h);
}

__device__ __forceinline__ void cp16(const short* g, short* l) {
  __builtin_amdgcn_global_load_lds(
      (const __attribute__((address_space(1))) void*)g,
      (__attribute__((address_space(3))) void*)l, 16, 0, 0);
}

// bijective XCD-chunked remap; requires nblk % 8 == 0.
__device__ __forceinline__ int xcd_swz(int x, int nblk) {
  return (x & 7) * (nblk >> 3) + (x >> 3);
}

// ---------------- fused fp32 -> bf16 conversion, 16 slices of 1M elems
// 32B load + 16B store per lane.
__global__ __launch_bounds__(256) void cvt_kernel(
    const float* q, const float* k, const float* v,
    const float* Wq, const float* Wk, const float* Wv, const float* Wo,
    short* qb, short* kb, short* vb,
    short* Wqb, short* Wkb, short* Wvb, short* Wob) {
  const int y = blockIdx.y;
  const float* s; short* d;
  if (y < 12) {
    const int t = y >> 2;
    const size_t off = (size_t)(y & 3) << 20;
    s = (t == 0 ? q : (t == 1 ? k : v)) + off;
    d = (t == 0 ? qb : (t == 1 ? kb : vb)) + off;
  } else {
    s = (y == 12 ? Wq : (y == 13 ? Wk : (y == 14 ? Wv : Wo)));
    d = (y == 12 ? Wqb : (y == 13 ? Wkb : (y == 14 ? Wvb : Wob)));
  }
  size_t i = (size_t)blockIdx.x * 256 + threadIdx.x;   // bf16x8 index
  const float4* s4 = (const float4*)s;
  float4 v0 = s4[2 * i];
  float4 v1 = s4[2 * i + 1];
  bf16x8 o;
  o[0] = f2bf(v0.x); o[1] = f2bf(v0.y); o[2] = f2bf(v0.z); o[3] = f2bf(v0.w);
  o[4] = f2bf(v1.x); o[5] = f2bf(v1.y); o[6] = f2bf(v1.z); o[7] = f2bf(v1.w);
  ((bf16x8*)d)[i] = o;
}

// ---------------- fused Q/K/V projection GEMM: C = (A @ W^T + b) * scale
// 128x128 tile, BK=32 x 32 rounds, triple-buffered counted-vmcnt pipeline.
// LDS panels quad-swizzled: physical quad = logical ^ ((row>>1)&3).
__global__ __launch_bounds__(256) void gemm_qkv(
    const short* __restrict__ A0, const short* __restrict__ A1, const short* __restrict__ A2,
    const short* __restrict__ W0, const short* __restrict__ W1, const short* __restrict__ W2,
    const float* __restrict__ b0, const float* __restrict__ b1, const float* __restrict__ b2,
    short* __restrict__ C0, short* __restrict__ C1, short* __restrict__ Cv) {
  __shared__ short As[3][128 * 32];
  __shared__ short Bs[3][128 * 32];
  const int which = blockIdx.y;
  const short* A    = which == 0 ? A0 : (which == 1 ? A1 : A2);
  const short* W    = which == 0 ? W0 : (which == 1 ? W1 : W2);
  const float* bias = which == 0 ? b0 : (which == 1 ? b1 : b2);
  const float scale = which == 0 ? 0.18033688011112042f : 1.0f;  // 0.125*log2e

  const int tid  = threadIdx.x;
  const int bx   = xcd_swz((int)blockIdx.x, 256);  // XCD owns 4 bm x 8 bn chunk
  const int bm   = bx >> 3;
  const int bn   = bx & 7;
  const int lane = tid & 63, wid = tid >> 6;
  const int g = lane >> 4, l15 = lane & 15;
  const int wm = (wid >> 1) * 64, wn = (wid & 1) * 64;
  const int sk = (l15 >> 1) & 3;                   // read-side swizzle key

  const int qsw = ((tid & 3) ^ ((tid >> 3) & 3)) * 8;
  const short* Ag = A + (size_t)(bm * 128 + (tid >> 2)) * 1024 + qsw;
  const short* Wg = W + (size_t)(bn * 128 + (tid >> 2)) * 1024 + qsw;
  const int wofs = wid * 512;

  // stage round t (cols t*32..t*32+31) into buffer b: 4 vmem instrs/wave
#define QKV_STAGE(t, b)                               \
  do {                                                \
    const int kk_ = (t) * 32;                         \
    cp16(Ag + kk_,             As[(b)] + wofs);       \
    cp16(Ag + 64 * 1024 + kk_, As[(b)] + wofs + 2048);\
    cp16(Wg + kk_,             Bs[(b)] + wofs);       \
    cp16(Wg + 64 * 1024 + kk_, Bs[(b)] + wofs + 2048);\
  } while (0)

  f32x4 acc[4][4];
#pragma unroll
  for (int i = 0; i < 4; ++i)
#pragma unroll
    for (int j = 0; j < 4; ++j) acc[i][j] = (f32x4){0.f, 0.f, 0.f, 0.f};

  QKV_STAGE(0, 0);
  QKV_STAGE(1, 1);

  for (int t = 0; t < 32; ++t) {
    const int cur = t % 3;
    if (t < 30) {
      QKV_STAGE(t + 2, (t + 2) % 3);
      asm volatile("s_waitcnt vmcnt(8)" ::: "memory");   // round-t loads done
    } else if (t == 30) {
      asm volatile("s_waitcnt vmcnt(4)" ::: "memory");
    } else {
      asm volatile("s_waitcnt vmcnt(0)" ::: "memory");
    }
    __builtin_amdgcn_s_barrier();

    bf16x8 af[4], bfr[4];
#pragma unroll
    for (int mt = 0; mt < 4; ++mt)
      af[mt] = *(const bf16x8*)&As[cur][(wm + mt * 16 + l15) * 32 + ((g ^ sk)) * 8];
#pragma unroll
    for (int nt = 0; nt < 4; ++nt)
      bfr[nt] = *(const bf16x8*)&Bs[cur][(wn + nt * 16 + l15) * 32 + ((g ^ sk)) * 8];
#pragma unroll
    for (int mt = 0; mt < 4; ++mt)
#pragma unroll
      for (int nt = 0; nt < 4; ++nt)
        acc[mt][nt] = __builtin_amdgcn_mfma_f32_16x16x32_bf16(
            af[mt], bfr[nt], acc[mt][nt], 0, 0, 0);

    asm volatile("s_waitcnt lgkmcnt(0)" ::: "memory");   // LDS reads retired
    __builtin_amdgcn_s_barrier();                        // vmcnt NOT drained
  }
#undef QKV_STAGE

  const int col0 = bn * 128 + wn;
  if (which < 2) {
    short* C = which == 0 ? C0 : C1;
#pragma unroll
    for (int nt = 0; nt < 4; ++nt) {
      const int col = col0 + nt * 16 + l15;
      const float bb = bias[col];
#pragma unroll
      for (int mt = 0; mt < 4; ++mt) {
        const int m0 = bm * 128 + wm + mt * 16 + g * 4;
#pragma unroll
        for (int r = 0; r < 4; ++r)
          C[(size_t)(m0 + r) * 1024 + col] = f2bf((acc[mt][nt][r] + bb) * scale);
      }
    }
  } else {
    // V: write transposed per head [b,h,dh,slot], key-dim c-permuted within
    // each 64-key tile: c(k6) = (nt6&2)*16 + g6*8 + (nt6&1)*4 + r6, matching
    // attn's in-register P fragment slot order.
#pragma unroll
    for (int nt = 0; nt < 4; ++nt) {
      const int col = col0 + nt * 16 + l15;
      const int h = col >> 6, dh = col & 63;
      const float bb = bias[col];
#pragma unroll
      for (int mt = 0; mt < 4; ++mt) {
        const int m0 = bm * 128 + wm + mt * 16 + g * 4;   // 4-aligned, same b
        const int bb_ = m0 >> 11, s0 = m0 & 2047;
        const int k6 = s0 & 63;                           // k6&3 == 0
        const int cpos = (s0 & ~63) | (((k6 >> 4) & 2) << 4)
                       | (((k6 >> 2) & 3) << 3) | (((k6 >> 4) & 1) << 2);
        bf16x4 o;
#pragma unroll
        for (int r = 0; r < 4; ++r) o[r] = f2bf(acc[mt][nt][r] + bb);
        *(bf16x4*)&Cv[(((size_t)bb_ * 16 + h) * 64 + dh) * 2048 + cpos] = o;
      }
    }
  }
}

// ---------------- output projection: fp32 out = A(bf16) @ W^T + b
// 64x128 tile, BK=64 x 16 rounds, double-buffered counted-vmcnt pipeline.
// [*][64] panels, 8-chunk XOR swizzle: phys chunk = logical ^ (row&7);
// source pre-swizzled qc = (l&7)^(l>>3); reads at (kh*4+g)^(l15&7) ->
// consecutive-8-lane groups hit all 8 bank-quads (conflict-free).
__global__ __launch_bounds__(256) void gemm_out(
    const short* __restrict__ A, const short* __restrict__ W,
    const float* __restrict__ bias, float* __restrict__ C) {
  __shared__ short As[2][64 * 64];    // 16 KB
  __shared__ short Bs[2][128 * 64];   // 32 KB
  const int tid  = threadIdx.x;
  const int bx   = xcd_swz((int)blockIdx.x, 512);  // XCD owns 8 bm x 8 bn chunk
  const int bm   = bx >> 3;    // 64 M-tiles
  const int bn   = bx & 7;     // 8 N-tiles
  const int lane = tid & 63, wid = tid >> 6;
  const int g = lane >> 4, l15 = lane & 15;
  const int wm = (wid >> 1) * 32, wn = (wid & 1) * 64;
  const int sx8 = l15 & 7;

  // staging: lane l covers row base+(l>>3), physical chunk l&7; source chunk
  // (l&7)^(l>>3) so physical chunk p at row r holds logical p^(r&7).
  const int lrow = lane >> 3;
  const int qc   = (lane & 7) ^ lrow;
  const short* Ag = A + (size_t)(bm * 64 + wid * 16 + lrow) * 1024 + qc * 8;
  const short* Wg = W + (size_t)(bn * 128 + wid * 8 + lrow) * 1024 + qc * 8;

  // stage round t (cols t*64..t*64+63) into buffer b: 6 vmem instrs/thread
#define OUT_STAGE(t, b)                                     \
  do {                                                      \
    const int kk_ = (t) * 64;                               \
    cp16(Ag + kk_,             As[(b)] + wid * 1024);       \
    cp16(Ag + 8 * 1024 + kk_,  As[(b)] + wid * 1024 + 512); \
    cp16(Wg + kk_,             Bs[(b)] + wid * 512);        \
    cp16(Wg + 32 * 1024 + kk_, Bs[(b)] + wid * 512 + 2048); \
    cp16(Wg + 64 * 1024 + kk_, Bs[(b)] + wid * 512 + 4096); \
    cp16(Wg + 96 * 1024 + kk_, Bs[(b)] + wid * 512 + 6144); \
  } while (0)

  f32x4 acc[2][4];
#pragma unroll
  for (int i = 0; i < 2; ++i)
#pragma unroll
    for (int j = 0; j < 4; ++j) acc[i][j] = (f32x4){0.f, 0.f, 0.f, 0.f};

  OUT_STAGE(0, 0);

  for (int t = 0; t < 16; ++t) {
    const int cur = t & 1;
    if (t < 15) {
      OUT_STAGE(t + 1, cur ^ 1);
      asm volatile("s_waitcnt vmcnt(6)" ::: "memory");   // round-t loads done
    } else {
      asm volatile("s_waitcnt vmcnt(0)" ::: "memory");
    }
    __builtin_amdgcn_s_barrier();

#pragma unroll
    for (int kh = 0; kh < 2; ++kh) {
      const int c8 = ((kh * 4 + g) ^ sx8) * 8;
      bf16x8 af[2], bfr[4];
#pragma unroll
      for (int mt = 0; mt < 2; ++mt)
        af[mt] = *(const bf16x8*)&As[cur][(wm + mt * 16 + l15) * 64 + c8];
#pragma unroll
      for (int nt = 0; nt < 4; ++nt)
        bfr[nt] = *(const bf16x8*)&Bs[cur][(wn + nt * 16 + l15) * 64 + c8];
#pragma unroll
      for (int mt = 0; mt < 2; ++mt)
#pragma unroll
        for (int nt = 0; nt < 4; ++nt)
          acc[mt][nt] = __builtin_amdgcn_mfma_f32_16x16x32_bf16(
              af[mt], bfr[nt], acc[mt][nt], 0, 0, 0);
    }

    asm volatile("s_waitcnt lgkmcnt(0)" ::: "memory");
    __builtin_amdgcn_s_barrier();                        // vmcnt NOT drained
  }
#undef OUT_STAGE

  const int col0 = bn * 128 + wn;
#pragma unroll
  for (int nt = 0; nt < 4; ++nt) {
    const int col = col0 + nt * 16 + l15;
    const float bb = bias[col];
#pragma unroll
    for (int mt = 0; mt < 2; ++mt) {
      const int m0 = bm * 64 + wm + mt * 16 + g * 4;
#pragma unroll
      for (int r = 0; r < 4; ++r)
        C[(size_t)(m0 + r) * 1024 + col] = acc[mt][nt][r] + bb;
    }
  }
}

// ---------------- flash attention, static-max exp2 softmax, full keys.
// 512 threads / 8 waves: waves 0-3 even K/V tiles, 4-7 odd (16 rounds each).
// Per wave: 32 q-rows, in-register P (swapped QK^T + c-ordered V), DMA
// staging with counted vmcnt(4), XOR quad-swizzled [64][64] tiles
// (conflicts=0). Partial O/l merged additively in LDS epilogue.
__global__ __launch_bounds__(512, 4) void attn_kernel(
    const short* __restrict__ Q, const short* __restrict__ K,
    const short* __restrict__ Vg, short* __restrict__ O) {
  __shared__ __align__(16) char smem[65536];
  short (*KT)[2][64 * 64] = (short(*)[2][64 * 64])smem;            // [par][buf]
  short (*VT)[2][64 * 64] = (short(*)[2][64 * 64])(smem + 32768);  // [par][buf]
  float* M = (float*)smem;                                         // epilogue

  const int tid  = threadIdx.x;
  const int bx   = xcd_swz((int)blockIdx.x, 512);  // XCD owns 4 (b,h) groups
  const int qt   = bx & 15;    // 16 q-tiles of 128 rows
  const int bh   = bx >> 4;    // 32 (b,h)
  const int b    = bh >> 4, h = bh & 15;
  const int lane = tid & 63, wid = tid >> 6;   // wid 0..7
  const int par  = wid >> 2;                   // key-tile parity group
  const int w4   = wid & 3;                    // q-subtile within group
  const int g = lane >> 4, l15 = lane & 15;
  const int sx = l15 & 7;                      // read-side swizzle key

  const int q0 = qt * 128 + w4 * 32;
  bf16x8 qf[2][2];
#pragma unroll
  for (int mt = 0; mt < 2; ++mt) {
    const size_t base = (size_t)(b * 2048 + q0 + mt * 16 + l15) * 1024 + h * 64;
    qf[mt][0] = *(const bf16x8*)(Q + base + g * 8);
    qf[mt][1] = *(const bf16x8*)(Q + base + 32 + g * 8);
  }

  // O^T accumulator: o_acc[mt][nt][r] = O[q = mt*16+l15][dh = nt*16+g*4+r]
  f32x4 o_acc[2][4];
#pragma unroll
  for (int i = 0; i < 2; ++i)
#pragma unroll
    for (int j = 0; j < 4; ++j) o_acc[i][j] = (f32x4){0.f, 0.f, 0.f, 0.f};
  float l_i[2] = {0.f, 0.f};

  // DMA staging: each parity's wave w4 owns rows w4*16..w4*16+15 of its tile.
  const int lrow = lane >> 3;
  const int qc   = (lane & 7) ^ lrow;
  const int r0   = w4 * 16;
  const short* KgA = K + (size_t)(b * 2048 + r0 + lrow) * 1024 + h * 64 + qc * 8;
  const short* VgA = Vg + (size_t)((b * 16 + h) * 64 + r0 + lrow) * 2048 + qc * 8;

#define ATTN_STAGE(tk_, bf_)                                                  \
  do {                                                                        \
    cp16(KgA + (size_t)(tk_) * 64 * 1024,       &KT[par][bf_][r0 * 64]);      \
    cp16(KgA + (size_t)((tk_) * 64 + 8) * 1024, &KT[par][bf_][(r0 + 8) * 64]);\
    cp16(VgA + (tk_) * 64,                      &VT[par][bf_][r0 * 64]);      \
    cp16(VgA + (tk_) * 64 + 8 * 2048,           &VT[par][bf_][(r0 + 8) * 64]);\
  } while (0)

  ATTN_STAGE(par, 0);

  for (int ktp = 0; ktp < 16; ++ktp) {
    const int cur = ktp & 1;
    if (ktp < 15) {
      ATTN_STAGE(2 * (ktp + 1) + par, cur ^ 1);
      asm volatile("s_waitcnt vmcnt(4)" ::: "memory");   // this round's loads
    } else {
      asm volatile("s_waitcnt vmcnt(0)" ::: "memory");
    }
    __builtin_amdgcn_s_barrier();

    // S^T = K Q^T (exp2 domain): lane holds S[key=nt*16+g*4+r][q=mt*16+l15]
    f32x4 sv[2][4];
    __builtin_amdgcn_s_setprio(1);
#pragma unroll
    for (int nt = 0; nt < 4; ++nt) {
      const int krow = (nt * 16 + l15) * 64;
      bf16x8 kf0 = *(const bf16x8*)&KT[par][cur][krow + ((g ^ sx) << 3)];
      bf16x8 kf1 = *(const bf16x8*)&KT[par][cur][krow + (((g + 4) ^ sx) << 3)];
#pragma unroll
      for (int mt = 0; mt < 2; ++mt) {
        f32x4 z = (f32x4){0.f, 0.f, 0.f, 0.f};
        z = __builtin_amdgcn_mfma_f32_16x16x32_bf16(kf0, qf[mt][0], z, 0, 0, 0);
        z = __builtin_amdgcn_mfma_f32_16x16x32_bf16(kf1, qf[mt][1], z, 0, 0, 0);
        sv[mt][nt] = z;
      }
    }
    __builtin_amdgcn_s_setprio(0);

    // static-max softmax in-register: p = exp2(s); lane's 16 values pack
    // into its PV B-frag (slot c = (nt&2)*16 + g*8 + (nt&1)*4 + r)
    bf16x8 pf[2][2];
#pragma unroll
    for (int mt = 0; mt < 2; ++mt) {
      float s = 0.f;
#pragma unroll
      for (int nt = 0; nt < 4; ++nt)
#pragma unroll
        for (int r = 0; r < 4; ++r) {
          float p = EXP2(sv[mt][nt][r]);
          s += p;
          pf[mt][nt >> 1][(nt & 1) * 4 + r] = f2bf(p);
        }
      l_i[mt] += s;
    }

    // O^T += V^T P^T : A = vf (dh rows, c slots), B = pf (q cols, c slots)
    __builtin_amdgcn_s_setprio(1);
#pragma unroll
    for (int nt = 0; nt < 4; ++nt) {
      const int vrow = (nt * 16 + l15) * 64;
      bf16x8 vf0 = *(const bf16x8*)&VT[par][cur][vrow + ((g ^ sx) << 3)];
      bf16x8 vf1 = *(const bf16x8*)&VT[par][cur][vrow + (((g + 4) ^ sx) << 3)];
#pragma unroll
      for (int mt = 0; mt < 2; ++mt) {
        o_acc[mt][nt] = __builtin_amdgcn_mfma_f32_16x16x32_bf16(
            vf0, pf[mt][0], o_acc[mt][nt], 0, 0, 0);
        o_acc[mt][nt] = __builtin_amdgcn_mfma_f32_16x16x32_bf16(
            vf1, pf[mt][1], o_acc[mt][nt], 0, 0, 0);
      }
    }
    __builtin_amdgcn_s_setprio(0);

    asm volatile("s_waitcnt lgkmcnt(0)" ::: "memory");   // LDS reads retired
    __builtin_amdgcn_s_barrier();                        // vmcnt NOT drained
  }
#undef ATTN_STAGE

  // merge parity-1 partials into parity-0 via LDS (34 floats, stride 36)
  if (par == 1) {
    float* dst = M + (size_t)(w4 * 64 + lane) * 36;
#pragma unroll
    for (int mt = 0; mt < 2; ++mt)
#pragma unroll
      for (int nt = 0; nt < 4; ++nt)
        *(f32x4*)(dst + (mt * 4 + nt) * 4) = o_acc[mt][nt];
    dst[32] = l_i[0];
    dst[33] = l_i[1];
  }
  __syncthreads();
  if (par == 0) {
    const float* src = M + (size_t)(w4 * 64 + lane) * 36;
#pragma unroll
    for (int mt = 0; mt < 2; ++mt)
#pragma unroll
      for (int nt = 0; nt < 4; ++nt)
        o_acc[mt][nt] += *(const f32x4*)(src + (mt * 4 + nt) * 4);
    l_i[0] += src[32];
    l_i[1] += src[33];

    // epilogue: reduce l across the 4 g-groups, normalize, store bf16x4
#pragma unroll
    for (int mt = 0; mt < 2; ++mt) {
      float l = l_i[mt];
      l += __shfl_xor(l, 16, 64);
      l += __shfl_xor(l, 32, 64);
      const float inv = 1.0f / l;
      const int row = q0 + mt * 16 + l15;
      const size_t base = (size_t)(b * 2048 + row) * 1024 + h * 64;
#pragma unroll
      for (int nt = 0; nt < 4; ++nt) {
        bf16x4 o;
#pragma unroll
        for (int r = 0; r < 4; ++r) o[r] = f2bf(o_acc[mt][nt][r] * inv);
        *(bf16x4*)&O[base + nt * 16 + g * 4] = o;
      }
    }
  }
}

extern "C" void kernel_launch(void* const* d_in, const int* in_sizes, int n_in,
                              void* d_out, int out_size, void* d_ws, size_t ws_size,
                              hipStream_t stream) {
  (void)in_sizes; (void)n_in; (void)out_size; (void)ws_size;
  const float* q  = (const float*)d_in[0];
  const float* k  = (const float*)d_in[1];
  const float* v  = (const float*)d_in[2];
  const float* Wq = (const float*)d_in[3];
  const float* bq = (const float*)d_in[4];
  const float* Wk = (const float*)d_in[5];
  const float* bk = (const float*)d_in[6];
  const float* Wv = (const float*)d_in[7];
  const float* bv = (const float*)d_in[8];
  const float* Wo = (const float*)d_in[9];
  const float* bo = (const float*)d_in[10];
  float* out = (float*)d_out;

  short* qb  = (short*)d_ws;       // bf16 inputs
  short* kb  = qb + NE;
  short* vb  = kb + NE;
  short* Wqb = vb + NE;            // bf16 weights
  short* Wkb = Wqb + NW;
  short* Wvb = Wkb + NW;
  short* Wob = Wvb + NW;
  short* Qw  = Wob + NW;           // projected Q (pre-scaled)
  short* Kw  = Qw + NE;
  short* Vtg = Kw + NE;            // projected V [b,h,dh,slot] (c-ordered)
  short* Ob  = qb;                 // attention out (qb dead after gemm_qkv)

  cvt_kernel<<<dim3(512, 16), 256, 0, stream>>>(q, k, v, Wq, Wk, Wv, Wo,
                                                qb, kb, vb, Wqb, Wkb, Wvb, Wob);
  gemm_qkv<<<dim3(256, 3), 256, 0, stream>>>(qb, kb, vb, Wqb, Wkb, Wvb,
                                             bq, bk, bv, Qw, Kw, Vtg);
  attn_kernel<<<512, 512, 0, stream>>>(Qw, Kw, Vtg, Ob);
  gemm_out<<<512, 256, 0, stream>>>(Ob, Wob, bo, out);
}